// Round 14
// baseline (956.506 us; speedup 1.0000x reference)
//
#include <hip/hip_runtime.h>
#include <hip/hip_bf16.h>
#include <cstdint>
#include <cstddef>

#define NEG_SLOPE 0.2f

using frag = __attribute__((ext_vector_type(8))) short;   // 8 bf16 = 4 VGPRs
using facc = __attribute__((ext_vector_type(4))) float;   // 4 fp32 accum

__device__ __forceinline__ float bf_hi(unsigned u) {
    union { unsigned i; float f; } t; t.i = u & 0xffff0000u; return t.f;
}
__device__ __forceinline__ float bf_lo(unsigned u) {
    union { unsigned i; float f; } t; t.i = u << 16; return t.f;
}
__device__ __forceinline__ void unpack8(uint4 u, float* v) {
    v[0] = bf_lo(u.x); v[1] = bf_hi(u.x);
    v[2] = bf_lo(u.y); v[3] = bf_hi(u.y);
    v[4] = bf_lo(u.z); v[5] = bf_hi(u.z);
    v[6] = bf_lo(u.w); v[7] = bf_hi(u.w);
}

// ---------------------------------------------------------------- CSR build
__global__ void count_kernel(const int* __restrict__ dstv, int* __restrict__ cnt, int E) {
    int e = blockIdx.x * blockDim.x + threadIdx.x;
    if (e < E) atomicAdd(&cnt[dstv[e]], 1);
}

// 3-phase parallel exclusive scan
__global__ void scan_phase1(const int* __restrict__ in, int* __restrict__ out,
                            int* __restrict__ bsum, int n) {
    __shared__ int buf[1024];
    int tid = threadIdx.x;
    int i = blockIdx.x * 1024 + tid;
    int v = (i < n) ? in[i] : 0;
    buf[tid] = v;
    __syncthreads();
    for (int off = 1; off < 1024; off <<= 1) {
        int t = (tid >= off) ? buf[tid - off] : 0;
        __syncthreads();
        buf[tid] += t;
        __syncthreads();
    }
    if (i < n) out[i] = buf[tid] - v;           // exclusive
    if (tid == 1023) bsum[blockIdx.x] = buf[1023];
}

__global__ void scan_phase2(int* __restrict__ bsum, int B) {
    __shared__ int buf[1024];
    int tid = threadIdx.x;
    int v = (tid < B) ? bsum[tid] : 0;
    buf[tid] = v;
    __syncthreads();
    for (int off = 1; off < 1024; off <<= 1) {
        int t = (tid >= off) ? buf[tid - off] : 0;
        __syncthreads();
        buf[tid] += t;
        __syncthreads();
    }
    if (tid < B) bsum[tid] = buf[tid] - v;      // exclusive block offsets
    if (tid == 0) bsum[B] = buf[B - 1];         // total
}

__global__ void scan_phase3(int* __restrict__ out, const int* __restrict__ bsum,
                            int n, int B) {
    int i = blockIdx.x * 1024 + threadIdx.x;
    if (i < n) out[i] += bsum[i >> 10];
    else if (i == n) out[n] = bsum[B];
}

__global__ void scatter_kernel(const int* __restrict__ srcv, const int* __restrict__ dstv,
                               int* __restrict__ cursor, int* __restrict__ colv, int E) {
    int e = blockIdx.x * blockDim.x + threadIdx.x;
    if (e < E) {
        int p = atomicAdd(&cursor[dstv[e]], 1);
        colv[p] = srcv[e];
    }
}

// ---------------------------------------------------------------- bf16 MFMA GEMM
// C[M,N] (bf16) = A[M,Kp] @ Bt[N,Kp]^T.  A,Bt bf16 row-major, Kp%32==0, N%128==0.
__global__ __launch_bounds__(256)
void gemm_bf16_mfma(const __hip_bfloat16* __restrict__ A,
                    const __hip_bfloat16* __restrict__ Bt,
                    __hip_bfloat16* __restrict__ C, int M, int N, int Kp) {
    __shared__ __hip_bfloat16 As[128 * 32];
    __shared__ __hip_bfloat16 Bs[128 * 32];
    int tid = threadIdx.x;
    int lane = tid & 63;
    int wave = tid >> 6;
    int wm = wave >> 1, wn = wave & 1;
    int quad = lane >> 4, l16 = lane & 15;
    int m0 = blockIdx.y * 128;
    int n0 = blockIdx.x * 128;

    facc acc[4][4] = {};

    for (int k0 = 0; k0 < Kp; k0 += 32) {
#pragma unroll
        for (int p = 0; p < 2; ++p) {
            int idx = p * 256 + tid;          // 0..511 -> 16B chunk id
            int row = idx >> 2;               // 0..127
            int koff = (idx & 3) * 8;         // element offset in 32-elem row
            int gr = m0 + row; if (gr >= M) gr = M - 1;
            frag va = *reinterpret_cast<const frag*>(A + (size_t)gr * Kp + k0 + koff);
            frag vb = *reinterpret_cast<const frag*>(Bt + (size_t)(n0 + row) * Kp + k0 + koff);
            *reinterpret_cast<frag*>(As + row * 32 + koff) = va;
            *reinterpret_cast<frag*>(Bs + row * 32 + koff) = vb;
        }
        __syncthreads();

        frag a[4], b[4];
#pragma unroll
        for (int i = 0; i < 4; ++i) {
            a[i] = *reinterpret_cast<const frag*>(As + (wm * 64 + i * 16 + l16) * 32 + quad * 8);
            b[i] = *reinterpret_cast<const frag*>(Bs + (wn * 64 + i * 16 + l16) * 32 + quad * 8);
        }
#pragma unroll
        for (int i = 0; i < 4; ++i)
#pragma unroll
            for (int j = 0; j < 4; ++j)
                acc[i][j] = __builtin_amdgcn_mfma_f32_16x16x32_bf16(a[i], b[j], acc[i][j], 0, 0, 0);
        __syncthreads();
    }

    // C/D layout: col = lane&15, row = quad*4 + reg
#pragma unroll
    for (int i = 0; i < 4; ++i)
#pragma unroll
        for (int j = 0; j < 4; ++j) {
            int col = n0 + wn * 64 + j * 16 + l16;
#pragma unroll
            for (int r = 0; r < 4; ++r) {
                int row = m0 + wm * 64 + i * 16 + quad * 4 + r;
                if (row < M) C[(size_t)row * N + col] = __float2bfloat16(acc[i][j][r]);
            }
        }
}

// YL/YR[M,2] fp32 = A[M,K](bf16) @ {Wl,Wr}[K,2](fp32) — one pass over A
__global__ void gemm_n22_b(const __hip_bfloat16* __restrict__ A,
                           const float* __restrict__ Wl, const float* __restrict__ Wr,
                           float* __restrict__ YL, float* __restrict__ YR, int M, int K) {
    int i = blockIdx.x * blockDim.x + threadIdx.x;
    if (i >= M) return;
    float l0 = 0.f, l1 = 0.f, r0 = 0.f, r1 = 0.f;
    const unsigned* a = (const unsigned*)(A + (size_t)i * K);
    for (int k2 = 0; k2 < K / 2; ++k2) {
        unsigned u = a[k2];
        float v0 = bf_lo(u), v1 = bf_hi(u);
        int k = k2 * 2;
        l0 = fmaf(v0, Wl[k * 2 + 0], l0);
        l1 = fmaf(v0, Wl[k * 2 + 1], l1);
        l0 = fmaf(v1, Wl[k * 2 + 2], l0);
        l1 = fmaf(v1, Wl[k * 2 + 3], l1);
        r0 = fmaf(v0, Wr[k * 2 + 0], r0);
        r1 = fmaf(v0, Wr[k * 2 + 1], r1);
        r0 = fmaf(v1, Wr[k * 2 + 2], r0);
        r1 = fmaf(v1, Wr[k * 2 + 3], r1);
    }
    YL[(size_t)i * 2 + 0] = l0;
    YL[(size_t)i * 2 + 1] = l1;
    YR[(size_t)i * 2 + 0] = r0;
    YR[(size_t)i * 2 + 1] = r1;
}

// ---------------------------------------------------------------- converters
__global__ void wconv(const float* __restrict__ W, __hip_bfloat16* __restrict__ Wt,
                      int K, int N, int Kp) {
    int i = blockIdx.x * blockDim.x + threadIdx.x;
    if (i >= N * Kp) return;
    int n = i / Kp, k = i - n * Kp;
    Wt[i] = __float2bfloat16((k < K) ? W[(size_t)k * N + n] : 0.f);
}

// h1 weight with permuted K: EHB layout is [gat(0..127) | z | pad31].
__global__ void wconv_h1(const float* __restrict__ W, __hip_bfloat16* __restrict__ Wt, int N) {
    int i = blockIdx.x * blockDim.x + threadIdx.x;
    if (i >= N * 160) return;
    int n = i / 160, k = i - n * 160;
    float v = 0.f;
    if (k < 128) v = W[(size_t)(k + 1) * N + n];
    else if (k == 128) v = W[n];
    Wt[i] = __float2bfloat16(v);
}

__global__ void xconv(const float* __restrict__ x, __hip_bfloat16* __restrict__ xb, int n) {
    int i = blockIdx.x * blockDim.x + threadIdx.x;
    if (i >= n * 128) return;
    int r = i >> 7, c = i & 127;
    xb[i] = __float2bfloat16((c < 125) ? x[(size_t)r * 125 + c] : 0.f);
}

__global__ void outer_xr_b(const float* __restrict__ xh, const float* __restrict__ w,
                           __hip_bfloat16* __restrict__ xr, int n) {
    int i = blockIdx.x * blockDim.x + threadIdx.x;
    if (i < n * 128) {
        int r = i >> 7, c = i & 127;
        xr[i] = __float2bfloat16(xh[r] * w[c]);
    }
}

__global__ void set_colz(const float* __restrict__ z, __hip_bfloat16* __restrict__ buf, int n) {
    int i = blockIdx.x * blockDim.x + threadIdx.x;
    if (i < n) buf[(size_t)i * 160 + 128] = __float2bfloat16(z[i]);
}

// ---------------------------------------------------------------- fused GATv2 edge phase v4
// One wave per (dst, head). 4 edges in flight (g=lane>>4), lane q=lane&15 owns
// channels 8q..8q+7 (one dwordx4 gather per edge). Pipelined gathers (depth 2).
// No online max: logits are O(3 sigma), fp32 exp overflows at 88 — plain
// exp(min(p,85)) is exact to rounding. Invalid slots: p=-inf -> exp=0.
__global__ void gat_c128_v4(const __hip_bfloat16* __restrict__ xl, int xls,
                            const __hip_bfloat16* __restrict__ xr, int xrs,
                            const int* __restrict__ row_off, const int* __restrict__ col,
                            const float* __restrict__ att, const float* __restrict__ bias,
                            __hip_bfloat16* __restrict__ outb, int obstride,
                            int n_dst, int H) {
    int wid = (blockIdx.x * blockDim.x + threadIdx.x) >> 6;
    int lane = threadIdx.x & 63;
    int total = n_dst * H;
    if (wid >= total) return;
    int dst = wid / H;
    int h = wid - dst * H;
    int g = lane >> 4;        // edge slot 0..3
    int q = lane & 15;        // channel block: channels 8q..8q+7
    int cb = h * 128 + q * 8;
    int beg = row_off[dst], end = row_off[dst + 1];

    float xrv[8], av[8];
    unpack8(*(const uint4*)(xr + (size_t)dst * xrs + cb), xrv);
    {
        float4 a0 = *(const float4*)(att + cb);
        float4 a1 = *(const float4*)(att + cb + 4);
        av[0] = a0.x; av[1] = a0.y; av[2] = a0.z; av[3] = a0.w;
        av[4] = a1.x; av[5] = a1.y; av[6] = a1.z; av[7] = a1.w;
    }

    float s = 0.f;
    float acc[8] = {0.f, 0.f, 0.f, 0.f, 0.f, 0.f, 0.f, 0.f};

    if (beg < end) {
        // prologue: chunk0 row data, chunk1 col index
        int e0g = beg + g;
        bool pv = e0g < end;
        int i0 = col[pv ? e0g : beg];
        uint4 u = *(const uint4*)(xl + (size_t)i0 * xls + cb);
        int e1g = beg + 4 + g;
        int i1 = (beg + 4 < end) ? col[(e1g < end) ? e1g : beg] : 0;

        for (int e0 = beg; e0 < end; e0 += 4) {
            bool have_next = (e0 + 4) < end;
            uint4 un;
            if (have_next)
                un = *(const uint4*)(xl + (size_t)i1 * xls + cb);   // issue early
            int e2g = e0 + 8 + g;
            int i2 = (e0 + 8 < end) ? col[(e2g < end) ? e2g : beg] : 0;
            bool nv = (e0 + 4 + g) < end;

            // process current chunk
            float v[8];
            unpack8(u, v);
            float p = 0.f;
#pragma unroll
            for (int c = 0; c < 8; ++c) {
                float z = v[c] + xrv[c];
                z = fmaxf(z, NEG_SLOPE * z);    // leaky-relu, slope<1
                p = fmaf(z, av[c], p);
            }
            p += __shfl_xor(p, 8, 64);
            p += __shfl_xor(p, 4, 64);
            p += __shfl_xor(p, 2, 64);
            p += __shfl_xor(p, 1, 64);
            if (!pv) p = -INFINITY;
            float w = __expf(fminf(p, 85.f));   // 0 for invalid slots
            s += w;
#pragma unroll
            for (int c = 0; c < 8; ++c) acc[c] = fmaf(w, v[c], acc[c]);

            if (have_next) { u = un; pv = nv; }
            i1 = i2;
        }
    }

    // merge the 4 edge-groups (lane^16 / lane^32 hold matching channels)
#pragma unroll
    for (int o = 16; o <= 32; o <<= 1) {
        s += __shfl_xor(s, o, 64);
#pragma unroll
        for (int c = 0; c < 8; ++c) acc[c] += __shfl_xor(acc[c], o, 64);
    }

    int deg = end - beg;
    float inv = (deg > 0) ? 1.f / (s * (float)deg) : 0.f;
    float o8[8];
#pragma unroll
    for (int c = 0; c < 8; ++c) o8[c] = acc[c] * inv;
    if (bias != nullptr) {
#pragma unroll
        for (int c = 0; c < 8; ++c) o8[c] += bias[cb + c];
    }
    if (g == 0) {
        union { uint4 u; __hip_bfloat16 hh[8]; } pk;
#pragma unroll
        for (int c = 0; c < 8; ++c) pk.hh[c] = __float2bfloat16(o8[c]);
        *(uint4*)(outb + (size_t)dst * obstride + cb) = pk.u;
    }
}

// C=2, H=1 final layer: one thread per dst (fp32 xl/xr).
__global__ void gat_c2(const float* __restrict__ xl, const float* __restrict__ xr,
                       const int* __restrict__ row_off, const int* __restrict__ col,
                       const float* __restrict__ att, const float* __restrict__ bias,
                       float* __restrict__ out, int n_dst) {
    int dst = blockIdx.x * blockDim.x + threadIdx.x;
    if (dst >= n_dst) return;
    float x0 = xr[(size_t)dst * 2], x1 = xr[(size_t)dst * 2 + 1];
    float a0 = att[0], a1 = att[1];
    int beg = row_off[dst], end = row_off[dst + 1];
    float s = 0.f, acc0 = 0.f, acc1 = 0.f;
    for (int e = beg; e < end; ++e) {
        int src = col[e];
        float v0 = xl[(size_t)src * 2], v1 = xl[(size_t)src * 2 + 1];
        float z0 = v0 + x0; z0 = fmaxf(z0, NEG_SLOPE * z0);
        float z1 = v1 + x1; z1 = fmaxf(z1, NEG_SLOPE * z1);
        float p = fmaf(z0, a0, z1 * a1);
        float w = __expf(fminf(p, 85.f));
        s += w;
        acc0 = fmaf(w, v0, acc0);
        acc1 = fmaf(w, v1, acc1);
    }
    int deg = end - beg;
    float o0 = 0.f, o1 = 0.f;
    if (deg > 0) {
        float inv = 1.f / (s * (float)deg);
        o0 = acc0 * inv;
        o1 = acc1 * inv;
    }
    out[(size_t)dst * 2 + 0] = o0 + bias[0];
    out[(size_t)dst * 2 + 1] = o1 + bias[1];
}

// ---------------------------------------------------------------- BatchNorm (deterministic)
// Stage 1: 256 blocks write per-block partial sums (NO atomics -> replay-stable).
__global__ void bn_partial_d(const __hip_bfloat16* __restrict__ x, float* __restrict__ part,
                             int Nr, int rpb) {
    int C = blockDim.x;
    int c = threadIdx.x;
    int b = blockIdx.x;
    int r0 = b * rpb;
    int r1 = r0 + rpb; if (r1 > Nr) r1 = Nr;
    float s = 0.f, q = 0.f;
    for (int r = r0; r < r1; ++r) {
        float v = __bfloat162float(x[(size_t)r * C + c]);
        s += v;
        q = fmaf(v, v, q);
    }
    part[(size_t)b * C + c] = s;
    part[65536 + (size_t)b * C + c] = q;   // 256*256 slot offset
}

// Stage 2: fixed-order sum of 256 partials per channel -> scale/shift.
__global__ void bn_finalize_d(const float* __restrict__ part,
                              const float* __restrict__ g, const float* __restrict__ b,
                              float* __restrict__ scale, float* __restrict__ shift,
                              int Nr, int C) {
    int c = threadIdx.x;
    float s = 0.f, q = 0.f;
    for (int blk = 0; blk < 256; ++blk) {
        s += part[(size_t)blk * C + c];
        q += part[65536 + (size_t)blk * C + c];
    }
    float mu = s / (float)Nr;
    float var = q / (float)Nr - mu * mu;
    float inv = rsqrtf(var + 1e-5f);
    float a = g[c] * inv;
    scale[c] = a;
    shift[c] = b[c] - mu * a;
}

__global__ void bn_apply_b(__hip_bfloat16* __restrict__ x, const float* __restrict__ scale,
                           const float* __restrict__ shift, long n, int Cmask) {
    long i = (long)blockIdx.x * blockDim.x + threadIdx.x;
    if (i < n) {
        int c = (int)(i & Cmask);
        float v = fmaf(__bfloat162float(x[i]), scale[c], shift[c]);
        x[i] = __float2bfloat16(v);
    }
}

// ---------------------------------------------------------------- driver
extern "C" void kernel_launch(void* const* d_in, const int* in_sizes, int n_in,
                              void* d_out, int out_size, void* d_ws, size_t ws_size,
                              hipStream_t stream) {
    const float* x_low  = (const float*)d_in[0];
    const float* x_high = (const float*)d_in[1];
    const float* z_std  = (const float*)d_in[2];
    const int* e_low  = (const int*)d_in[3];
    const int* e_l2h  = (const int*)d_in[4];
    const int* e_high = (const int*)d_in[5];
    const float* l1_Wl = (const float*)d_in[6];
    const float* l1_Wr = (const float*)d_in[7];
    const float* l1_att = (const float*)d_in[8];
    const float* l1_b  = (const float*)d_in[9];
    const float* bn1_g = (const float*)d_in[10];
    const float* bn1_b = (const float*)d_in[11];
    const float* l2_Wl = (const float*)d_in[12];
    const float* l2_Wr = (const float*)d_in[13];
    const float* l2_att = (const float*)d_in[14];
    const float* l2_b  = (const float*)d_in[15];
    const float* bn2_g = (const float*)d_in[16];
    const float* bn2_b = (const float*)d_in[17];
    const float* l3_Wl = (const float*)d_in[18];
    const float* l3_Wr = (const float*)d_in[19];
    const float* l3_att = (const float*)d_in[20];
    const float* l3_b  = (const float*)d_in[21];
    const float* lh_Wl = (const float*)d_in[22];
    const float* lh_Wr = (const float*)d_in[23];
    const float* lh_att = (const float*)d_in[24];
    const float* h1_Wl = (const float*)d_in[25];
    const float* h1_Wr = (const float*)d_in[26];
    const float* h1_att = (const float*)d_in[27];
    const float* h1_b  = (const float*)d_in[28];
    const float* bn3_g = (const float*)d_in[29];
    const float* bn3_b = (const float*)d_in[30];
    const float* h2_Wl = (const float*)d_in[31];
    const float* h2_Wr = (const float*)d_in[32];
    const float* h2_att = (const float*)d_in[33];
    const float* h2_b  = (const float*)d_in[34];
    const float* bn4_g = (const float*)d_in[35];
    const float* bn4_b = (const float*)d_in[36];
    const float* h3_Wl = (const float*)d_in[37];
    const float* h3_Wr = (const float*)d_in[38];
    const float* h3_att = (const float*)d_in[39];
    const float* h3_b  = (const float*)d_in[40];

    const int N_low = in_sizes[0] / 125;
    const int N_high = in_sizes[1];
    const int E_low = in_sizes[3] / 2;
    const int E_l2h = in_sizes[4] / 2;
    const int E_high = in_sizes[5] / 2;

    char* ws = (char*)d_ws;
    size_t woff = 0;
    auto walloc = [&](size_t bytes) -> void* {
        void* p = (void*)(ws + woff);
        woff += (bytes + 255) & ~(size_t)255;
        return p;
    };
    // XLR holds merged [XL|XR] GEMM outputs (max N_high x 512 bf16 = 61 MB)
    __hip_bfloat16* XLR = (__hip_bfloat16*)walloc((size_t)N_high * 512 * 2);
    __hip_bfloat16* A1  = (__hip_bfloat16*)walloc((size_t)N_high * 256 * 2);
    __hip_bfloat16* A2  = (__hip_bfloat16*)walloc((size_t)N_high * 128 * 2);
    __hip_bfloat16* XRo = (__hip_bfloat16*)walloc((size_t)N_high * 128 * 2); // lh outer xr
    __hip_bfloat16* XLOWB = (__hip_bfloat16*)walloc((size_t)N_low * 128 * 2);
    __hip_bfloat16* EHB = (__hip_bfloat16*)walloc((size_t)N_high * 160 * 2);
    float* YL = (float*)walloc((size_t)N_high * 2 * 4);
    float* YR = (float*)walloc((size_t)N_high * 2 * 4);
    int* off_low  = (int*)walloc((size_t)(N_low + 1) * 4);
    int* col_low  = (int*)walloc((size_t)E_low * 4);
    int* off_l2h  = (int*)walloc((size_t)(N_high + 1) * 4);
    int* col_l2h  = (int*)walloc((size_t)E_l2h * 4);
    int* off_high = (int*)walloc((size_t)(N_high + 1) * 4);
    int* col_high = (int*)walloc((size_t)E_high * 4);
    int* cursor   = (int*)walloc((size_t)(N_high + 1) * 4);
    int* bsum     = (int*)walloc(1025 * 4);
    float* bnpart = (float*)walloc(2 * 256 * 256 * 4);   // deterministic BN partials
    float* bnsc   = (float*)walloc(512 * 4);
    // merged [Wl|Wr] bf16 transposed weights [Ncat][Kp]
    __hip_bfloat16* w_l1 = (__hip_bfloat16*)walloc(512 * 128 * 2);
    __hip_bfloat16* w_l2 = (__hip_bfloat16*)walloc(256 * 256 * 2);
    __hip_bfloat16* w_l3 = (__hip_bfloat16*)walloc(256 * 128 * 2);
    __hip_bfloat16* w_lh = (__hip_bfloat16*)walloc(128 * 128 * 2);
    __hip_bfloat16* w_h1 = (__hip_bfloat16*)walloc(512 * 160 * 2);
    __hip_bfloat16* w_h2 = (__hip_bfloat16*)walloc(256 * 256 * 2);

    // ---- weight & input conversion (tiny)
    auto wc = [&](const float* W, __hip_bfloat16* Wt, int K, int N, int Kp) {
        int n = N * Kp;
        wconv<<<(n + 255) / 256, 256, 0, stream>>>(W, Wt, K, N, Kp);
    };
    wc(l1_Wl, w_l1, 125, 256, 128);  wc(l1_Wr, w_l1 + 256 * 128, 125, 256, 128);
    wc(l2_Wl, w_l2, 256, 128, 256);  wc(l2_Wr, w_l2 + 128 * 256, 256, 128, 256);
    wc(l3_Wl, w_l3, 128, 128, 128);  wc(l3_Wr, w_l3 + 128 * 128, 128, 128, 128);
    wc(lh_Wl, w_lh, 128, 128, 128);
    wconv_h1<<<(256 * 160 + 255) / 256, 256, 0, stream>>>(h1_Wl, w_h1, 256);
    wconv_h1<<<(256 * 160 + 255) / 256, 256, 0, stream>>>(h1_Wr, w_h1 + 256 * 160, 256);
    wc(h2_Wl, w_h2, 256, 128, 256);  wc(h2_Wr, w_h2 + 128 * 256, 256, 128, 256);
    xconv<<<((size_t)N_low * 128 + 255) / 256, 256, 0, stream>>>(x_low, XLOWB, N_low);

    // ---- CSR build (parallel 3-phase scan)
    auto build_csr = [&](const int* edges, int E, int Nn, int* roff, int* colv) {
        hipMemsetAsync(cursor, 0, (size_t)Nn * 4, stream);
        count_kernel<<<(E + 255) / 256, 256, 0, stream>>>(edges + E, cursor, E);
        int B = (Nn + 1023) / 1024;
        scan_phase1<<<B, 1024, 0, stream>>>(cursor, roff, bsum, Nn);
        scan_phase2<<<1, 1024, 0, stream>>>(bsum, B);
        scan_phase3<<<(Nn + 1 + 1023) / 1024, 1024, 0, stream>>>(roff, bsum, Nn, B);
        hipMemcpyAsync(cursor, roff, (size_t)Nn * 4, hipMemcpyDeviceToDevice, stream);
        scatter_kernel<<<(E + 255) / 256, 256, 0, stream>>>(edges, edges + E, cursor, colv, E);
    };
    build_csr(e_low, E_low, N_low, off_low, col_low);
    build_csr(e_l2h, E_l2h, N_high, off_l2h, col_l2h);
    build_csr(e_high, E_high, N_high, off_high, col_high);

    auto gemm = [&](const __hip_bfloat16* A, const __hip_bfloat16* Bt, __hip_bfloat16* C,
                    int M, int N, int Kp) {
        dim3 g(N / 128, (M + 127) / 128);
        gemm_bf16_mfma<<<g, 256, 0, stream>>>(A, Bt, C, M, N, Kp);
    };
    auto gat = [&](const __hip_bfloat16* xl, int xls, const __hip_bfloat16* xr, int xrs,
                   const int* roff, const int* colv,
                   const float* att, const float* bias,
                   __hip_bfloat16* outb, int obs, int n_dst, int H) {
        long thr = (long)n_dst * H * 64;
        gat_c128_v4<<<(unsigned)((thr + 255) / 256), 256, 0, stream>>>(
            xl, xls, xr, xrs, roff, colv, att, bias, outb, obs, n_dst, H);
    };
    // deterministic BN: partials (no atomics) -> fixed-order finalize -> apply
    auto bn = [&](__hip_bfloat16* x, const float* g, const float* b, int Nr, int C) {
        int rpb = (Nr + 255) / 256;
        bn_partial_d<<<256, C, 0, stream>>>(x, bnpart, Nr, rpb);
        bn_finalize_d<<<1, C, 0, stream>>>(bnpart, g, b, bnsc, bnsc + 256, Nr, C);
        long n = (long)Nr * C;
        bn_apply_b<<<(unsigned)((n + 255) / 256), 256, 0, stream>>>(x, bnsc, bnsc + 256, n, C - 1);
    };

    // ---- low_net layer 1: 125 -> (H=2) 256, BN   (merged [XL|XR], stride 512)
    gemm(XLOWB, w_l1, XLR, N_low, 512, 128);
    gat(XLR, 512, XLR + 256, 512, off_low, col_low, l1_att, l1_b, A1, 256, N_low, 2);
    bn(A1, bn1_g, bn1_b, N_low, 256);

    // ---- low_net layer 2: 256 -> 128, BN   (merged, stride 256)
    gemm(A1, w_l2, XLR, N_low, 256, 256);
    gat(XLR, 256, XLR + 128, 256, off_low, col_low, l2_att, l2_b, A2, 128, N_low, 1);
    bn(A2, bn2_g, bn2_b, N_low, 128);

    // ---- low_net layer 3: 128 -> 128   (merged, stride 256)
    gemm(A2, w_l3, XLR, N_low, 256, 128);
    gat(XLR, 256, XLR + 128, 256, off_low, col_low, l3_att, l3_b, A1, 128, N_low, 1);

    // ---- bipartite low2high -> EHB[N_high][160] = [gat 0..127 | z | pad]
    gemm(A1, w_lh, XLR, N_low, 128, 128);   // xl only, stride 128
    outer_xr_b<<<(unsigned)(((size_t)N_high * 128 + 255) / 256), 256, 0, stream>>>(x_high, lh_Wr, XRo, N_high);
    hipMemsetAsync(EHB, 0, (size_t)N_high * 160 * 2, stream);
    gat(XLR, 128, XRo, 128, off_l2h, col_l2h, lh_att, nullptr, EHB, 160, N_high, 1);
    set_colz<<<(N_high + 255) / 256, 256, 0, stream>>>(z_std, EHB, N_high);

    // ---- high_net layer 1: 129(perm,pad160) -> (H=2) 256, BN   (merged, stride 512)
    gemm(EHB, w_h1, XLR, N_high, 512, 160);
    gat(XLR, 512, XLR + 256, 512, off_high, col_high, h1_att, h1_b, A1, 256, N_high, 2);
    bn(A1, bn3_g, bn3_b, N_high, 256);

    // ---- high_net layer 2: 256 -> 128, BN   (merged, stride 256)
    gemm(A1, w_h2, XLR, N_high, 256, 256);
    gat(XLR, 256, XLR + 128, 256, off_high, col_high, h2_att, h2_b, A2, 128, N_high, 1);
    bn(A2, bn4_g, bn4_b, N_high, 128);

    // ---- high_net layer 3: 128 -> 2 (one pass over A2 for both Wl and Wr)
    gemm_n22_b<<<(N_high + 255) / 256, 256, 0, stream>>>(A2, h3_Wl, h3_Wr, YL, YR, N_high, 128);
    gat_c2<<<(N_high + 255) / 256, 256, 0, stream>>>(YL, YR, off_high, col_high,
                                                     h3_att, h3_b, (float*)d_out, N_high);
}

// Round 15
// 889.317 us; speedup vs baseline: 1.0756x; 1.0756x over previous
//
#include <hip/hip_runtime.h>
#include <hip/hip_bf16.h>
#include <cstdint>
#include <cstddef>

#define NEG_SLOPE 0.2f

using frag = __attribute__((ext_vector_type(8))) short;   // 8 bf16 = 4 VGPRs
using facc = __attribute__((ext_vector_type(4))) float;   // 4 fp32 accum

__device__ __forceinline__ float bf_hi(unsigned u) {
    union { unsigned i; float f; } t; t.i = u & 0xffff0000u; return t.f;
}
__device__ __forceinline__ float bf_lo(unsigned u) {
    union { unsigned i; float f; } t; t.i = u << 16; return t.f;
}
__device__ __forceinline__ void unpack8(uint4 u, float* v) {
    v[0] = bf_lo(u.x); v[1] = bf_hi(u.x);
    v[2] = bf_lo(u.y); v[3] = bf_hi(u.y);
    v[4] = bf_lo(u.z); v[5] = bf_hi(u.z);
    v[6] = bf_lo(u.w); v[7] = bf_hi(u.w);
}

// ---------------------------------------------------------------- CSR build
__global__ void count_kernel(const int* __restrict__ dstv, int* __restrict__ cnt, int E) {
    int e = blockIdx.x * blockDim.x + threadIdx.x;
    if (e < E) atomicAdd(&cnt[dstv[e]], 1);
}

// 3-phase parallel exclusive scan
__global__ void scan_phase1(const int* __restrict__ in, int* __restrict__ out,
                            int* __restrict__ bsum, int n) {
    __shared__ int buf[1024];
    int tid = threadIdx.x;
    int i = blockIdx.x * 1024 + tid;
    int v = (i < n) ? in[i] : 0;
    buf[tid] = v;
    __syncthreads();
    for (int off = 1; off < 1024; off <<= 1) {
        int t = (tid >= off) ? buf[tid - off] : 0;
        __syncthreads();
        buf[tid] += t;
        __syncthreads();
    }
    if (i < n) out[i] = buf[tid] - v;           // exclusive
    if (tid == 1023) bsum[blockIdx.x] = buf[1023];
}

__global__ void scan_phase2(int* __restrict__ bsum, int B) {
    __shared__ int buf[1024];
    int tid = threadIdx.x;
    int v = (tid < B) ? bsum[tid] : 0;
    buf[tid] = v;
    __syncthreads();
    for (int off = 1; off < 1024; off <<= 1) {
        int t = (tid >= off) ? buf[tid - off] : 0;
        __syncthreads();
        buf[tid] += t;
        __syncthreads();
    }
    if (tid < B) bsum[tid] = buf[tid] - v;      // exclusive block offsets
    if (tid == 0) bsum[B] = buf[B - 1];         // total
}

__global__ void scan_phase3(int* __restrict__ out, const int* __restrict__ bsum,
                            int n, int B) {
    int i = blockIdx.x * 1024 + threadIdx.x;
    if (i < n) out[i] += bsum[i >> 10];
    else if (i == n) out[n] = bsum[B];
}

__global__ void scatter_kernel(const int* __restrict__ srcv, const int* __restrict__ dstv,
                               int* __restrict__ cursor, int* __restrict__ colv, int E) {
    int e = blockIdx.x * blockDim.x + threadIdx.x;
    if (e < E) {
        int p = atomicAdd(&cursor[dstv[e]], 1);
        colv[p] = srcv[e];
    }
}

// ---------------------------------------------------------------- bf16 MFMA GEMM
// C[M,N] (bf16) = A[M,Kp] @ Bt[N,Kp]^T.  A,Bt bf16 row-major, Kp%32==0, N%128==0.
__global__ __launch_bounds__(256)
void gemm_bf16_mfma(const __hip_bfloat16* __restrict__ A,
                    const __hip_bfloat16* __restrict__ Bt,
                    __hip_bfloat16* __restrict__ C, int M, int N, int Kp) {
    __shared__ __hip_bfloat16 As[128 * 32];
    __shared__ __hip_bfloat16 Bs[128 * 32];
    int tid = threadIdx.x;
    int lane = tid & 63;
    int wave = tid >> 6;
    int wm = wave >> 1, wn = wave & 1;
    int quad = lane >> 4, l16 = lane & 15;
    int m0 = blockIdx.y * 128;
    int n0 = blockIdx.x * 128;

    facc acc[4][4] = {};

    for (int k0 = 0; k0 < Kp; k0 += 32) {
#pragma unroll
        for (int p = 0; p < 2; ++p) {
            int idx = p * 256 + tid;          // 0..511 -> 16B chunk id
            int row = idx >> 2;               // 0..127
            int koff = (idx & 3) * 8;         // element offset in 32-elem row
            int gr = m0 + row; if (gr >= M) gr = M - 1;
            frag va = *reinterpret_cast<const frag*>(A + (size_t)gr * Kp + k0 + koff);
            frag vb = *reinterpret_cast<const frag*>(Bt + (size_t)(n0 + row) * Kp + k0 + koff);
            *reinterpret_cast<frag*>(As + row * 32 + koff) = va;
            *reinterpret_cast<frag*>(Bs + row * 32 + koff) = vb;
        }
        __syncthreads();

        frag a[4], b[4];
#pragma unroll
        for (int i = 0; i < 4; ++i) {
            a[i] = *reinterpret_cast<const frag*>(As + (wm * 64 + i * 16 + l16) * 32 + quad * 8);
            b[i] = *reinterpret_cast<const frag*>(Bs + (wn * 64 + i * 16 + l16) * 32 + quad * 8);
        }
#pragma unroll
        for (int i = 0; i < 4; ++i)
#pragma unroll
            for (int j = 0; j < 4; ++j)
                acc[i][j] = __builtin_amdgcn_mfma_f32_16x16x32_bf16(a[i], b[j], acc[i][j], 0, 0, 0);
        __syncthreads();
    }

    // C/D layout: col = lane&15, row = quad*4 + reg
#pragma unroll
    for (int i = 0; i < 4; ++i)
#pragma unroll
        for (int j = 0; j < 4; ++j) {
            int col = n0 + wn * 64 + j * 16 + l16;
#pragma unroll
            for (int r = 0; r < 4; ++r) {
                int row = m0 + wm * 64 + i * 16 + quad * 4 + r;
                if (row < M) C[(size_t)row * N + col] = __float2bfloat16(acc[i][j][r]);
            }
        }
}

// YL/YR[M,2] fp32 = A[M,K](bf16) @ {Wl,Wr}[K,2](fp32) — one pass over A
__global__ void gemm_n22_b(const __hip_bfloat16* __restrict__ A,
                           const float* __restrict__ Wl, const float* __restrict__ Wr,
                           float* __restrict__ YL, float* __restrict__ YR, int M, int K) {
    int i = blockIdx.x * blockDim.x + threadIdx.x;
    if (i >= M) return;
    float l0 = 0.f, l1 = 0.f, r0 = 0.f, r1 = 0.f;
    const unsigned* a = (const unsigned*)(A + (size_t)i * K);
    for (int k2 = 0; k2 < K / 2; ++k2) {
        unsigned u = a[k2];
        float v0 = bf_lo(u), v1 = bf_hi(u);
        int k = k2 * 2;
        l0 = fmaf(v0, Wl[k * 2 + 0], l0);
        l1 = fmaf(v0, Wl[k * 2 + 1], l1);
        l0 = fmaf(v1, Wl[k * 2 + 2], l0);
        l1 = fmaf(v1, Wl[k * 2 + 3], l1);
        r0 = fmaf(v0, Wr[k * 2 + 0], r0);
        r1 = fmaf(v0, Wr[k * 2 + 1], r1);
        r0 = fmaf(v1, Wr[k * 2 + 2], r0);
        r1 = fmaf(v1, Wr[k * 2 + 3], r1);
    }
    YL[(size_t)i * 2 + 0] = l0;
    YL[(size_t)i * 2 + 1] = l1;
    YR[(size_t)i * 2 + 0] = r0;
    YR[(size_t)i * 2 + 1] = r1;
}

// ---------------------------------------------------------------- converters
__global__ void wconv(const float* __restrict__ W, __hip_bfloat16* __restrict__ Wt,
                      int K, int N, int Kp) {
    int i = blockIdx.x * blockDim.x + threadIdx.x;
    if (i >= N * Kp) return;
    int n = i / Kp, k = i - n * Kp;
    Wt[i] = __float2bfloat16((k < K) ? W[(size_t)k * N + n] : 0.f);
}

// h1 weight with permuted K: EHB layout is [gat(0..127) | z | pad31].
__global__ void wconv_h1(const float* __restrict__ W, __hip_bfloat16* __restrict__ Wt, int N) {
    int i = blockIdx.x * blockDim.x + threadIdx.x;
    if (i >= N * 160) return;
    int n = i / 160, k = i - n * 160;
    float v = 0.f;
    if (k < 128) v = W[(size_t)(k + 1) * N + n];
    else if (k == 128) v = W[n];
    Wt[i] = __float2bfloat16(v);
}

__global__ void xconv(const float* __restrict__ x, __hip_bfloat16* __restrict__ xb, int n) {
    int i = blockIdx.x * blockDim.x + threadIdx.x;
    if (i >= n * 128) return;
    int r = i >> 7, c = i & 127;
    xb[i] = __float2bfloat16((c < 125) ? x[(size_t)r * 125 + c] : 0.f);
}

__global__ void outer_xr_b(const float* __restrict__ xh, const float* __restrict__ w,
                           __hip_bfloat16* __restrict__ xr, int n) {
    int i = blockIdx.x * blockDim.x + threadIdx.x;
    if (i < n * 128) {
        int r = i >> 7, c = i & 127;
        xr[i] = __float2bfloat16(xh[r] * w[c]);
    }
}

__global__ void set_colz(const float* __restrict__ z, __hip_bfloat16* __restrict__ buf, int n) {
    int i = blockIdx.x * blockDim.x + threadIdx.x;
    if (i < n) buf[(size_t)i * 160 + 128] = __float2bfloat16(z[i]);
}

// ---------------------------------------------------------------- fused GATv2 edge phase v4
// One wave per (dst, head). 4 edges in flight (g=lane>>4), lane q=lane&15 owns
// channels 8q..8q+7 (one dwordx4 gather per edge). Pipelined gathers (depth 2).
// No online max: logits are O(3 sigma), fp32 exp overflows at 88 — plain
// exp(min(p,85)) is exact to rounding. Invalid slots: p=-inf -> exp=0.
__global__ void gat_c128_v4(const __hip_bfloat16* __restrict__ xl, int xls,
                            const __hip_bfloat16* __restrict__ xr, int xrs,
                            const int* __restrict__ row_off, const int* __restrict__ col,
                            const float* __restrict__ att, const float* __restrict__ bias,
                            __hip_bfloat16* __restrict__ outb, int obstride,
                            int n_dst, int H) {
    int wid = (blockIdx.x * blockDim.x + threadIdx.x) >> 6;
    int lane = threadIdx.x & 63;
    int total = n_dst * H;
    if (wid >= total) return;
    int dst = wid / H;
    int h = wid - dst * H;
    int g = lane >> 4;        // edge slot 0..3
    int q = lane & 15;        // channel block: channels 8q..8q+7
    int cb = h * 128 + q * 8;
    int beg = row_off[dst], end = row_off[dst + 1];

    float xrv[8], av[8];
    unpack8(*(const uint4*)(xr + (size_t)dst * xrs + cb), xrv);
    {
        float4 a0 = *(const float4*)(att + cb);
        float4 a1 = *(const float4*)(att + cb + 4);
        av[0] = a0.x; av[1] = a0.y; av[2] = a0.z; av[3] = a0.w;
        av[4] = a1.x; av[5] = a1.y; av[6] = a1.z; av[7] = a1.w;
    }

    float s = 0.f;
    float acc[8] = {0.f, 0.f, 0.f, 0.f, 0.f, 0.f, 0.f, 0.f};

    if (beg < end) {
        // prologue: chunk0 row data, chunk1 col index
        int e0g = beg + g;
        bool pv = e0g < end;
        int i0 = col[pv ? e0g : beg];
        uint4 u = *(const uint4*)(xl + (size_t)i0 * xls + cb);
        int e1g = beg + 4 + g;
        int i1 = (beg + 4 < end) ? col[(e1g < end) ? e1g : beg] : 0;

        for (int e0 = beg; e0 < end; e0 += 4) {
            bool have_next = (e0 + 4) < end;
            uint4 un;
            if (have_next)
                un = *(const uint4*)(xl + (size_t)i1 * xls + cb);   // issue early
            int e2g = e0 + 8 + g;
            int i2 = (e0 + 8 < end) ? col[(e2g < end) ? e2g : beg] : 0;
            bool nv = (e0 + 4 + g) < end;

            // process current chunk
            float v[8];
            unpack8(u, v);
            float p = 0.f;
#pragma unroll
            for (int c = 0; c < 8; ++c) {
                float z = v[c] + xrv[c];
                z = fmaxf(z, NEG_SLOPE * z);    // leaky-relu, slope<1
                p = fmaf(z, av[c], p);
            }
            p += __shfl_xor(p, 8, 64);
            p += __shfl_xor(p, 4, 64);
            p += __shfl_xor(p, 2, 64);
            p += __shfl_xor(p, 1, 64);
            if (!pv) p = -INFINITY;
            float w = __expf(fminf(p, 85.f));   // 0 for invalid slots
            s += w;
#pragma unroll
            for (int c = 0; c < 8; ++c) acc[c] = fmaf(w, v[c], acc[c]);

            if (have_next) { u = un; pv = nv; }
            i1 = i2;
        }
    }

    // merge the 4 edge-groups (lane^16 / lane^32 hold matching channels)
#pragma unroll
    for (int o = 16; o <= 32; o <<= 1) {
        s += __shfl_xor(s, o, 64);
#pragma unroll
        for (int c = 0; c < 8; ++c) acc[c] += __shfl_xor(acc[c], o, 64);
    }

    int deg = end - beg;
    float inv = (deg > 0) ? 1.f / (s * (float)deg) : 0.f;
    float o8[8];
#pragma unroll
    for (int c = 0; c < 8; ++c) o8[c] = acc[c] * inv;
    if (bias != nullptr) {
#pragma unroll
        for (int c = 0; c < 8; ++c) o8[c] += bias[cb + c];
    }
    if (g == 0) {
        union { uint4 u; __hip_bfloat16 hh[8]; } pk;
#pragma unroll
        for (int c = 0; c < 8; ++c) pk.hh[c] = __float2bfloat16(o8[c]);
        *(uint4*)(outb + (size_t)dst * obstride + cb) = pk.u;
    }
}

// C=2, H=1 final layer: one thread per dst (fp32 xl/xr).
__global__ void gat_c2(const float* __restrict__ xl, const float* __restrict__ xr,
                       const int* __restrict__ row_off, const int* __restrict__ col,
                       const float* __restrict__ att, const float* __restrict__ bias,
                       float* __restrict__ out, int n_dst) {
    int dst = blockIdx.x * blockDim.x + threadIdx.x;
    if (dst >= n_dst) return;
    float x0 = xr[(size_t)dst * 2], x1 = xr[(size_t)dst * 2 + 1];
    float a0 = att[0], a1 = att[1];
    int beg = row_off[dst], end = row_off[dst + 1];
    float s = 0.f, acc0 = 0.f, acc1 = 0.f;
    for (int e = beg; e < end; ++e) {
        int src = col[e];
        float v0 = xl[(size_t)src * 2], v1 = xl[(size_t)src * 2 + 1];
        float z0 = v0 + x0; z0 = fmaxf(z0, NEG_SLOPE * z0);
        float z1 = v1 + x1; z1 = fmaxf(z1, NEG_SLOPE * z1);
        float p = fmaf(z0, a0, z1 * a1);
        float w = __expf(fminf(p, 85.f));
        s += w;
        acc0 = fmaf(w, v0, acc0);
        acc1 = fmaf(w, v1, acc1);
    }
    int deg = end - beg;
    float o0 = 0.f, o1 = 0.f;
    if (deg > 0) {
        float inv = 1.f / (s * (float)deg);
        o0 = acc0 * inv;
        o1 = acc1 * inv;
    }
    out[(size_t)dst * 2 + 0] = o0 + bias[0];
    out[(size_t)dst * 2 + 1] = o1 + bias[1];
}

// ---------------------------------------------------------------- BatchNorm (deterministic)
// Stage 1: 256 blocks write per-block partial sums (NO atomics -> replay-stable).
__global__ void bn_partial_d(const __hip_bfloat16* __restrict__ x, float* __restrict__ part,
                             int Nr, int rpb) {
    int C = blockDim.x;
    int c = threadIdx.x;
    int b = blockIdx.x;
    int r0 = b * rpb;
    int r1 = r0 + rpb; if (r1 > Nr) r1 = Nr;
    float s = 0.f, q = 0.f;
    for (int r = r0; r < r1; ++r) {
        float v = __bfloat162float(x[(size_t)r * C + c]);
        s += v;
        q = fmaf(v, v, q);
    }
    part[(size_t)b * C + c] = s;
    part[65536 + (size_t)b * C + c] = q;   // 256*256 slot offset
}

// Stage 2: ONE WAVE PER CHANNEL, lanes sum 4 partials each, fixed-order
// shuffle tree -> deterministic AND parallel (C/4 blocks, not 1).
__global__ void bn_finalize_w(const float* __restrict__ part,
                              const float* __restrict__ g, const float* __restrict__ b,
                              float* __restrict__ scale, float* __restrict__ shift,
                              int Nr, int C) {
    int c = (blockIdx.x * blockDim.x + threadIdx.x) >> 6;
    int lane = threadIdx.x & 63;
    if (c >= C) return;
    float s = 0.f, q = 0.f;
    for (int blk = lane; blk < 256; blk += 64) {
        s += part[(size_t)blk * C + c];
        q += part[65536 + (size_t)blk * C + c];
    }
#pragma unroll
    for (int o = 32; o; o >>= 1) {
        s += __shfl_xor(s, o, 64);
        q += __shfl_xor(q, o, 64);
    }
    if (lane == 0) {
        float mu = s / (float)Nr;
        float var = q / (float)Nr - mu * mu;
        float inv = rsqrtf(var + 1e-5f);
        float a = g[c] * inv;
        scale[c] = a;
        shift[c] = b[c] - mu * a;
    }
}

__global__ void bn_apply_b(__hip_bfloat16* __restrict__ x, const float* __restrict__ scale,
                           const float* __restrict__ shift, long n, int Cmask) {
    long i = (long)blockIdx.x * blockDim.x + threadIdx.x;
    if (i < n) {
        int c = (int)(i & Cmask);
        float v = fmaf(__bfloat162float(x[i]), scale[c], shift[c]);
        x[i] = __float2bfloat16(v);
    }
}

// ---------------------------------------------------------------- driver
extern "C" void kernel_launch(void* const* d_in, const int* in_sizes, int n_in,
                              void* d_out, int out_size, void* d_ws, size_t ws_size,
                              hipStream_t stream) {
    const float* x_low  = (const float*)d_in[0];
    const float* x_high = (const float*)d_in[1];
    const float* z_std  = (const float*)d_in[2];
    const int* e_low  = (const int*)d_in[3];
    const int* e_l2h  = (const int*)d_in[4];
    const int* e_high = (const int*)d_in[5];
    const float* l1_Wl = (const float*)d_in[6];
    const float* l1_Wr = (const float*)d_in[7];
    const float* l1_att = (const float*)d_in[8];
    const float* l1_b  = (const float*)d_in[9];
    const float* bn1_g = (const float*)d_in[10];
    const float* bn1_b = (const float*)d_in[11];
    const float* l2_Wl = (const float*)d_in[12];
    const float* l2_Wr = (const float*)d_in[13];
    const float* l2_att = (const float*)d_in[14];
    const float* l2_b  = (const float*)d_in[15];
    const float* bn2_g = (const float*)d_in[16];
    const float* bn2_b = (const float*)d_in[17];
    const float* l3_Wl = (const float*)d_in[18];
    const float* l3_Wr = (const float*)d_in[19];
    const float* l3_att = (const float*)d_in[20];
    const float* l3_b  = (const float*)d_in[21];
    const float* lh_Wl = (const float*)d_in[22];
    const float* lh_Wr = (const float*)d_in[23];
    const float* lh_att = (const float*)d_in[24];
    const float* h1_Wl = (const float*)d_in[25];
    const float* h1_Wr = (const float*)d_in[26];
    const float* h1_att = (const float*)d_in[27];
    const float* h1_b  = (const float*)d_in[28];
    const float* bn3_g = (const float*)d_in[29];
    const float* bn3_b = (const float*)d_in[30];
    const float* h2_Wl = (const float*)d_in[31];
    const float* h2_Wr = (const float*)d_in[32];
    const float* h2_att = (const float*)d_in[33];
    const float* h2_b  = (const float*)d_in[34];
    const float* bn4_g = (const float*)d_in[35];
    const float* bn4_b = (const float*)d_in[36];
    const float* h3_Wl = (const float*)d_in[37];
    const float* h3_Wr = (const float*)d_in[38];
    const float* h3_att = (const float*)d_in[39];
    const float* h3_b  = (const float*)d_in[40];

    const int N_low = in_sizes[0] / 125;
    const int N_high = in_sizes[1];
    const int E_low = in_sizes[3] / 2;
    const int E_l2h = in_sizes[4] / 2;
    const int E_high = in_sizes[5] / 2;

    char* ws = (char*)d_ws;
    size_t woff = 0;
    auto walloc = [&](size_t bytes) -> void* {
        void* p = (void*)(ws + woff);
        woff += (bytes + 255) & ~(size_t)255;
        return p;
    };
    // XLR holds merged [XL|XR] GEMM outputs (max N_high x 512 bf16 = 61 MB)
    __hip_bfloat16* XLR = (__hip_bfloat16*)walloc((size_t)N_high * 512 * 2);
    __hip_bfloat16* A1  = (__hip_bfloat16*)walloc((size_t)N_high * 256 * 2);
    __hip_bfloat16* A2  = (__hip_bfloat16*)walloc((size_t)N_high * 128 * 2);
    __hip_bfloat16* XRo = (__hip_bfloat16*)walloc((size_t)N_high * 128 * 2); // lh outer xr
    __hip_bfloat16* XLOWB = (__hip_bfloat16*)walloc((size_t)N_low * 128 * 2);
    __hip_bfloat16* EHB = (__hip_bfloat16*)walloc((size_t)N_high * 160 * 2);
    float* YL = (float*)walloc((size_t)N_high * 2 * 4);
    float* YR = (float*)walloc((size_t)N_high * 2 * 4);
    int* off_low  = (int*)walloc((size_t)(N_low + 1) * 4);
    int* col_low  = (int*)walloc((size_t)E_low * 4);
    int* off_l2h  = (int*)walloc((size_t)(N_high + 1) * 4);
    int* col_l2h  = (int*)walloc((size_t)E_l2h * 4);
    int* off_high = (int*)walloc((size_t)(N_high + 1) * 4);
    int* col_high = (int*)walloc((size_t)E_high * 4);
    int* cursor   = (int*)walloc((size_t)(N_high + 1) * 4);
    int* bsum     = (int*)walloc(1025 * 4);
    float* bnpart = (float*)walloc(2 * 256 * 256 * 4);   // deterministic BN partials
    float* bnsc   = (float*)walloc(512 * 4);
    // merged [Wl|Wr] bf16 transposed weights [Ncat][Kp]
    __hip_bfloat16* w_l1 = (__hip_bfloat16*)walloc(512 * 128 * 2);
    __hip_bfloat16* w_l2 = (__hip_bfloat16*)walloc(256 * 256 * 2);
    __hip_bfloat16* w_l3 = (__hip_bfloat16*)walloc(256 * 128 * 2);
    __hip_bfloat16* w_lh = (__hip_bfloat16*)walloc(128 * 128 * 2);
    __hip_bfloat16* w_h1 = (__hip_bfloat16*)walloc(512 * 160 * 2);
    __hip_bfloat16* w_h2 = (__hip_bfloat16*)walloc(256 * 256 * 2);

    // ---- weight & input conversion (tiny)
    auto wc = [&](const float* W, __hip_bfloat16* Wt, int K, int N, int Kp) {
        int n = N * Kp;
        wconv<<<(n + 255) / 256, 256, 0, stream>>>(W, Wt, K, N, Kp);
    };
    wc(l1_Wl, w_l1, 125, 256, 128);  wc(l1_Wr, w_l1 + 256 * 128, 125, 256, 128);
    wc(l2_Wl, w_l2, 256, 128, 256);  wc(l2_Wr, w_l2 + 128 * 256, 256, 128, 256);
    wc(l3_Wl, w_l3, 128, 128, 128);  wc(l3_Wr, w_l3 + 128 * 128, 128, 128, 128);
    wc(lh_Wl, w_lh, 128, 128, 128);
    wconv_h1<<<(256 * 160 + 255) / 256, 256, 0, stream>>>(h1_Wl, w_h1, 256);
    wconv_h1<<<(256 * 160 + 255) / 256, 256, 0, stream>>>(h1_Wr, w_h1 + 256 * 160, 256);
    wc(h2_Wl, w_h2, 256, 128, 256);  wc(h2_Wr, w_h2 + 128 * 256, 256, 128, 256);
    xconv<<<((size_t)N_low * 128 + 255) / 256, 256, 0, stream>>>(x_low, XLOWB, N_low);

    // ---- CSR build (parallel 3-phase scan)
    auto build_csr = [&](const int* edges, int E, int Nn, int* roff, int* colv) {
        hipMemsetAsync(cursor, 0, (size_t)Nn * 4, stream);
        count_kernel<<<(E + 255) / 256, 256, 0, stream>>>(edges + E, cursor, E);
        int B = (Nn + 1023) / 1024;
        scan_phase1<<<B, 1024, 0, stream>>>(cursor, roff, bsum, Nn);
        scan_phase2<<<1, 1024, 0, stream>>>(bsum, B);
        scan_phase3<<<(Nn + 1 + 1023) / 1024, 1024, 0, stream>>>(roff, bsum, Nn, B);
        hipMemcpyAsync(cursor, roff, (size_t)Nn * 4, hipMemcpyDeviceToDevice, stream);
        scatter_kernel<<<(E + 255) / 256, 256, 0, stream>>>(edges, edges + E, cursor, colv, E);
    };
    build_csr(e_low, E_low, N_low, off_low, col_low);
    build_csr(e_l2h, E_l2h, N_high, off_l2h, col_l2h);
    build_csr(e_high, E_high, N_high, off_high, col_high);

    auto gemm = [&](const __hip_bfloat16* A, const __hip_bfloat16* Bt, __hip_bfloat16* C,
                    int M, int N, int Kp) {
        dim3 g(N / 128, (M + 127) / 128);
        gemm_bf16_mfma<<<g, 256, 0, stream>>>(A, Bt, C, M, N, Kp);
    };
    auto gat = [&](const __hip_bfloat16* xl, int xls, const __hip_bfloat16* xr, int xrs,
                   const int* roff, const int* colv,
                   const float* att, const float* bias,
                   __hip_bfloat16* outb, int obs, int n_dst, int H) {
        long thr = (long)n_dst * H * 64;
        gat_c128_v4<<<(unsigned)((thr + 255) / 256), 256, 0, stream>>>(
            xl, xls, xr, xrs, roff, colv, att, bias, outb, obs, n_dst, H);
    };
    // deterministic BN: no-atomic partials -> wave-per-channel fixed-tree finalize -> apply
    auto bn = [&](__hip_bfloat16* x, const float* g, const float* b, int Nr, int C) {
        int rpb = (Nr + 255) / 256;
        bn_partial_d<<<256, C, 0, stream>>>(x, bnpart, Nr, rpb);
        bn_finalize_w<<<(C * 64 + 255) / 256, 256, 0, stream>>>(bnpart, g, b, bnsc, bnsc + 256, Nr, C);
        long n = (long)Nr * C;
        bn_apply_b<<<(unsigned)((n + 255) / 256), 256, 0, stream>>>(x, bnsc, bnsc + 256, n, C - 1);
    };

    // ---- low_net layer 1: 125 -> (H=2) 256, BN   (merged [XL|XR], stride 512)
    gemm(XLOWB, w_l1, XLR, N_low, 512, 128);
    gat(XLR, 512, XLR + 256, 512, off_low, col_low, l1_att, l1_b, A1, 256, N_low, 2);
    bn(A1, bn1_g, bn1_b, N_low, 256);

    // ---- low_net layer 2: 256 -> 128, BN   (merged, stride 256)
    gemm(A1, w_l2, XLR, N_low, 256, 256);
    gat(XLR, 256, XLR + 128, 256, off_low, col_low, l2_att, l2_b, A2, 128, N_low, 1);
    bn(A2, bn2_g, bn2_b, N_low, 128);

    // ---- low_net layer 3: 128 -> 128   (merged, stride 256)
    gemm(A2, w_l3, XLR, N_low, 256, 128);
    gat(XLR, 256, XLR + 128, 256, off_low, col_low, l3_att, l3_b, A1, 128, N_low, 1);

    // ---- bipartite low2high -> EHB[N_high][160] = [gat 0..127 | z | pad]
    gemm(A1, w_lh, XLR, N_low, 128, 128);   // xl only, stride 128
    outer_xr_b<<<(unsigned)(((size_t)N_high * 128 + 255) / 256), 256, 0, stream>>>(x_high, lh_Wr, XRo, N_high);
    hipMemsetAsync(EHB, 0, (size_t)N_high * 160 * 2, stream);
    gat(XLR, 128, XRo, 128, off_l2h, col_l2h, lh_att, nullptr, EHB, 160, N_high, 1);
    set_colz<<<(N_high + 255) / 256, 256, 0, stream>>>(z_std, EHB, N_high);

    // ---- high_net layer 1: 129(perm,pad160) -> (H=2) 256, BN   (merged, stride 512)
    gemm(EHB, w_h1, XLR, N_high, 512, 160);
    gat(XLR, 512, XLR + 256, 512, off_high, col_high, h1_att, h1_b, A1, 256, N_high, 2);
    bn(A1, bn3_g, bn3_b, N_high, 256);

    // ---- high_net layer 2: 256 -> 128, BN   (merged, stride 256)
    gemm(A1, w_h2, XLR, N_high, 256, 256);
    gat(XLR, 256, XLR + 128, 256, off_high, col_high, h2_att, h2_b, A2, 128, N_high, 1);
    bn(A2, bn4_g, bn4_b, N_high, 128);

    // ---- high_net layer 3: 128 -> 2 (one pass over A2 for both Wl and Wr)
    gemm_n22_b<<<(N_high + 255) / 256, 256, 0, stream>>>(A2, h3_Wl, h3_Wr, YL, YR, N_high, 128);
    gat_c2<<<(N_high + 255) / 256, 256, 0, stream>>>(YL, YR, off_high, col_high,
                                                     h3_att, h3_b, (float*)d_out, N_high);
}